// Round 9
// baseline (291.183 us; speedup 1.0000x reference)
//
#include <hip/hip_runtime.h>
#include <math.h>

#define DIM 96
#define NHD 3
#define HD 32
#define NWT 343          // tokens per window
#define NWIN 128         // b * windows
#define TOK 43904        // total tokens = 2*28^3
#define NBIAS 2197       // (2*7-1)^3
#define SCALE 0.17677669529663687f
#define TPAD 352         // padded token count per window (22 tiles of 16)
#define TSZ  (343 * 352) // one (combo,head) bias slice, floats

typedef __attribute__((ext_vector_type(8))) short bf16x8;
typedef __attribute__((ext_vector_type(4))) float f32x4;

__device__ __forceinline__ unsigned short f2b(float f) {
    union { float f; unsigned int u; } x; x.f = f;
    unsigned int r = (x.u + 0x7fffu + ((x.u >> 16) & 1u)) >> 16;
    return (unsigned short)r;
}
__device__ __forceinline__ unsigned int pk2bf(float a, float b) {
    union { float f; unsigned int u; } x, y; x.f = a; y.f = b;
    return ((x.u + 0x8000u) >> 16) | ((y.u + 0x8000u) & 0xffff0000u);
}

// ---------------- K0: all fp32 -> bf16 weight conversion, one launch --------
__global__ void __launch_bounds__(256) k_cvt4(
        const float* __restrict__ s0, const float* __restrict__ s1,
        const float* __restrict__ s2, const float* __restrict__ s3,
        unsigned short* __restrict__ dst) {
    int i = blockIdx.x * 256 + threadIdx.x;
    if (i >= 221184) return;
    const float* src; int off;
    if (i < 55296)       { src = s0; off = i; }
    else if (i < 73728)  { src = s1; off = i - 55296; }
    else if (i < 147456) { src = s2; off = i - 73728; }
    else                 { src = s3; off = i - 147456; }
    dst[i] = f2b(src[off]);
}

// ---------------- K1: bias+mask+pad table -----------------------------------
// combo 0: layer0 (no mask). combos 1..8: layer1, type = combo-1 (edge bits d,h,w)
// layout: bt[((combo*3+head)*343 + q)*352 + k]; k>=343 -> -1e5 (exp -> 0)
__global__ void __launch_bounds__(256) k_bias(
        const float* __restrict__ rel0, const float* __restrict__ rel1,
        float* __restrict__ bt) {
    int i = blockIdx.x * 256 + threadIdx.x;
    if (i >= 9 * 3 * 343 * 352) return;
    int kcol = i % 352;
    int t = i / 352;
    int q = t % 343; t /= 343;
    int head = t % 3; int combo = t / 3;
    float outv;
    if (kcol >= 343) {
        outv = -100000.0f;
    } else {
        int dq = q / 49, hq = (q / 7) % 7, wq = q % 7;
        int dk = kcol / 49, hk = (kcol / 7) % 7, wk = kcol % 7;
        int ridx = (dq - dk + 6) * 169 + (hq - hk + 6) * 13 + (wq - wk + 6);
        const float* rel = (combo == 0) ? rel0 : rel1;
        float b = rel[ridx * 3 + head];
        if (combo > 0) {
            int ty = combo - 1;
            int rqd = (ty & 4) ? 1 + (dq >= 4) : 0;
            int rqh = (ty & 2) ? 1 + (hq >= 4) : 0;
            int rqw = (ty & 1) ? 1 + (wq >= 4) : 0;
            int rkd = (ty & 4) ? 1 + (dk >= 4) : 0;
            int rkh = (ty & 2) ? 1 + (hk >= 4) : 0;
            int rkw = (ty & 1) ? 1 + (wk >= 4) : 0;
            if (rqd != rkd || rqh != rkh || rqw != rkw) b -= 100.0f;
        }
        outv = b;
    }
    bt[i] = outv;
}

// ---------------- K2: fused LN1 + roll + partition + QKV MFMA ---------------
__global__ void __launch_bounds__(256) k_qkv(
        const float* __restrict__ x, const float* __restrict__ g1,
        const float* __restrict__ b1, const unsigned short* __restrict__ W,
        const float* __restrict__ bias, unsigned short* __restrict__ q,
        unsigned short* __restrict__ k, unsigned short* __restrict__ v, int shift) {
    __shared__ __align__(16) unsigned short lns[64][104];   // 13312 B
    __shared__ __align__(16) unsigned short wbuf[96][104];  // 19968 B
    int wid = threadIdx.x >> 6, lane = threadIdx.x & 63;
    int lm = lane & 15, q4 = lane >> 4;
    int m0 = blockIdx.x * 64 + wid * 16;
    int bwr[4], nnr[4];
    size_t rowoff[4];
    #pragma unroll
    for (int r = 0; r < 4; ++r) {
        int wtok = m0 + q4 * 4 + r;
        int bw = wtok / NWT, n = wtok % NWT;
        bwr[r] = bw; nnr[r] = n;
        int b = bw >> 6, win = bw & 63;
        int wdi = win >> 4, whi = (win >> 2) & 3, wwi = win & 3;
        int d = n / 49, h = (n / 7) % 7, w = n % 7;
        int sd = (wdi * 7 + d + shift) % 28;
        int sh = (whi * 7 + h + shift) % 28;
        int sw = (wwi * 7 + w + shift) % 28;
        rowoff[r] = (((size_t)(b * 28 + sd) * 28 + sh) * 28 + sw) * 96;
    }
    float val[6][4], g1v[6], b1v[6];
    #pragma unroll
    for (int c = 0; c < 6; ++c) {
        int ncol = c * 16 + lm;
        g1v[c] = g1[ncol]; b1v[c] = b1[ncol];
        #pragma unroll
        for (int r = 0; r < 4; ++r) val[c][r] = x[rowoff[r] + ncol];
    }
    #pragma unroll
    for (int r = 0; r < 4; ++r) {
        float s = 0.f, s2 = 0.f;
        #pragma unroll
        for (int c = 0; c < 6; ++c) { s += val[c][r]; s2 += val[c][r] * val[c][r]; }
        #pragma unroll
        for (int off = 8; off > 0; off >>= 1) {
            s  += __shfl_xor(s,  off, 64);
            s2 += __shfl_xor(s2, off, 64);
        }
        float mu = s * (1.0f / 96.0f);
        float rstd = rsqrtf(s2 * (1.0f / 96.0f) - mu * mu + 1e-5f);
        int row = wid * 16 + q4 * 4 + r;
        #pragma unroll
        for (int c = 0; c < 6; ++c)
            lns[row][c * 16 + lm] = f2b((val[c][r] - mu) * rstd * g1v[c] + b1v[c]);
    }
    __syncthreads();
    bf16x8 a1[3];
    #pragma unroll
    for (int ks = 0; ks < 3; ++ks)
        a1[ks] = *((const bf16x8*)&lns[wid * 16 + lm][ks * 32 + q4 * 8]);
    for (int ch = 0; ch < 3; ++ch) {
        __syncthreads();
        const uint4* src = (const uint4*)(W + ch * 96 * 96);
        for (int s = threadIdx.x; s < 1152; s += 256) {
            int row = s / 12, seg = s % 12;
            *((uint4*)&wbuf[row][seg * 8]) = src[s];
        }
        __syncthreads();
        f32x4 acc[6];
        #pragma unroll
        for (int c = 0; c < 6; ++c) acc[c] = (f32x4){0.f, 0.f, 0.f, 0.f};
        #pragma unroll
        for (int ks = 0; ks < 3; ++ks) {
            #pragma unroll
            for (int c = 0; c < 6; ++c) {
                bf16x8 b = *((const bf16x8*)&wbuf[c * 16 + lm][ks * 32 + q4 * 8]);
                acc[c] = __builtin_amdgcn_mfma_f32_16x16x32_bf16(a1[ks], b, acc[c], 0, 0, 0);
            }
        }
        #pragma unroll
        for (int c = 0; c < 6; ++c) {
            int col = c * 16 + lm;
            int head = col >> 5, hd = col & 31;
            float bb = bias[ch * 96 + col];
            #pragma unroll
            for (int r = 0; r < 4; ++r) {
                int wh = bwr[r] * NHD + head;
                float vv = acc[c][r] + bb;
                if (ch == 0)
                    q[(size_t)wh * (TPAD * 32) + nnr[r] * 32 + hd] = f2b(vv * SCALE);
                else if (ch == 1)
                    k[(size_t)wh * (TPAD * 32) + nnr[r] * 32 + hd] = f2b(vv);
                else
                    v[(size_t)wh * (32 * TPAD) + hd * TPAD + nnr[r]] = f2b(vv);
            }
        }
    }
}

// ---------------- K3: MFMA flash attention, precomputed bias table ----------
// grid = NWIN*NHD*3; each wave: 2 q-tiles. bias/mask/pad from bt (float4 loads)
__global__ void __launch_bounds__(256) k_attn(
        const unsigned short* __restrict__ q, const unsigned short* __restrict__ k,
        const unsigned short* __restrict__ vT, const float* __restrict__ bt,
        unsigned short* __restrict__ o, int tmul) {
    __shared__ __align__(16) unsigned short vts[32 * 360];
    __shared__ __align__(16) unsigned short pbuf[4][2][16 * 40];
    __shared__ float dnm[4][2][16];
    int wh = blockIdx.x / 3, third = blockIdx.x % 3;
    int bw = wh / NHD, head = wh % NHD;
    const unsigned int* vsrc = (const unsigned int*)(vT + (size_t)wh * 32 * TPAD);
    unsigned int* vdst = (unsigned int*)vts;
    for (int i = threadIdx.x; i < 32 * 176; i += 256) {
        int row = i / 176, cc = i - row * 176;
        vdst[row * 180 + cc] = vsrc[i];
    }
    __syncthreads();
    int win = bw & 63;
    int wdi = win >> 4, whi = (win >> 2) & 3, wwi = win & 3;
    int type = ((wdi == 3) ? 4 : 0) | ((whi == 3) ? 2 : 0) | ((wwi == 3) ? 1 : 0);
    const float* bbase = bt + (size_t)type * tmul + (size_t)head * TSZ;
    int wid = threadIdx.x >> 6, lane = threadIdx.x & 63;
    int lm = lane & 15, q4 = lane >> 4;
    int tb = third * 8 + wid * 2;
    if (tb > 21) return;               // no barriers below
    bool dual = (tb + 1 <= 21);
    int qtA = tb, qtB = dual ? tb + 1 : tb;
    const unsigned short* qbase = q + (size_t)wh * TPAD * 32;
    const unsigned short* kbase = k + (size_t)wh * TPAD * 32;
    int qtokA = qtA * 16 + lm, qtokB = qtB * 16 + lm;
    bf16x8 qfA = *((const bf16x8*)(qbase + qtokA * 32 + q4 * 8));
    bf16x8 qfB = *((const bf16x8*)(qbase + qtokB * 32 + q4 * 8));
    const float* bpA = bbase + (size_t)min(qtokA, NWT - 1) * 352;
    const float* bpB = bbase + (size_t)min(qtokB, NWT - 1) * 352;
    f32x4 aA0 = (f32x4){0.f,0.f,0.f,0.f}, aA1 = aA0, aB0 = aA0, aB1 = aA0;
    float dA = 0.f, dB = 0.f;
    unsigned short* pbA = pbuf[wid][0];
    unsigned short* pbB = pbuf[wid][1];
    for (int pr = 0; pr < 11; ++pr) {
        int kb0 = pr * 32;
        bf16x8 kf0 = *((const bf16x8*)(kbase + (kb0 + lm) * 32 + q4 * 8));
        bf16x8 kf1 = *((const bf16x8*)(kbase + (kb0 + 16 + lm) * 32 + q4 * 8));
        f32x4 bA0 = *((const f32x4*)(bpA + kb0 + q4 * 4));
        f32x4 bA1 = *((const f32x4*)(bpA + kb0 + 16 + q4 * 4));
        f32x4 bB0 = *((const f32x4*)(bpB + kb0 + q4 * 4));
        f32x4 bB1 = *((const f32x4*)(bpB + kb0 + 16 + q4 * 4));
        f32x4 z = (f32x4){0.f, 0.f, 0.f, 0.f};
        f32x4 sA0 = __builtin_amdgcn_mfma_f32_16x16x32_bf16(kf0, qfA, z, 0, 0, 0);
        f32x4 sA1 = __builtin_amdgcn_mfma_f32_16x16x32_bf16(kf1, qfA, z, 0, 0, 0);
        f32x4 sB0 = __builtin_amdgcn_mfma_f32_16x16x32_bf16(kf0, qfB, z, 0, 0, 0);
        f32x4 sB1 = __builtin_amdgcn_mfma_f32_16x16x32_bf16(kf1, qfB, z, 0, 0, 0);
        float pA[8], pB[8];
        #pragma unroll
        for (int r = 0; r < 4; ++r) {
            float a0 = __expf(sA0[r] + bA0[r]); dA += a0; pA[r] = a0;
            float a1 = __expf(sA1[r] + bA1[r]); dA += a1; pA[4 + r] = a1;
            float b0 = __expf(sB0[r] + bB0[r]); dB += b0; pB[r] = b0;
            float b1 = __expf(sB1[r] + bB1[r]); dB += b1; pB[4 + r] = b1;
        }
        #pragma unroll
        for (int t = 0; t < 2; ++t) {
            *((unsigned int*)(pbA + lm * 40 + t * 16 + q4 * 4)) =
                pk2bf(pA[t * 4 + 0], pA[t * 4 + 1]);
            *((unsigned int*)(pbA + lm * 40 + t * 16 + q4 * 4 + 2)) =
                pk2bf(pA[t * 4 + 2], pA[t * 4 + 3]);
            *((unsigned int*)(pbB + lm * 40 + t * 16 + q4 * 4)) =
                pk2bf(pB[t * 4 + 0], pB[t * 4 + 1]);
            *((unsigned int*)(pbB + lm * 40 + t * 16 + q4 * 4 + 2)) =
                pk2bf(pB[t * 4 + 2], pB[t * 4 + 3]);
        }
        bf16x8 pfA = *((const bf16x8*)(pbA + lm * 40 + q4 * 8));
        bf16x8 pfB = *((const bf16x8*)(pbB + lm * 40 + q4 * 8));
        bf16x8 v0 = *((const bf16x8*)(vts + lm * 360 + kb0 + q4 * 8));
        bf16x8 v1 = *((const bf16x8*)(vts + (16 + lm) * 360 + kb0 + q4 * 8));
        aA0 = __builtin_amdgcn_mfma_f32_16x16x32_bf16(pfA, v0, aA0, 0, 0, 0);
        aA1 = __builtin_amdgcn_mfma_f32_16x16x32_bf16(pfA, v1, aA1, 0, 0, 0);
        aB0 = __builtin_amdgcn_mfma_f32_16x16x32_bf16(pfB, v0, aB0, 0, 0, 0);
        aB1 = __builtin_amdgcn_mfma_f32_16x16x32_bf16(pfB, v1, aB1, 0, 0, 0);
    }
    dA += __shfl_xor(dA, 16, 64); dA += __shfl_xor(dA, 32, 64);
    dB += __shfl_xor(dB, 16, 64); dB += __shfl_xor(dB, 32, 64);
    if (lane < 16) { dnm[wid][0][lm] = dA; dnm[wid][1][lm] = dB; }
    #pragma unroll
    for (int r = 0; r < 4; ++r) {
        int qrowA = qtA * 16 + q4 * 4 + r;
        if (qrowA < NWT) {
            float inv = 1.0f / dnm[wid][0][q4 * 4 + r];
            unsigned short* op = o + (size_t)(bw * NWT + qrowA) * DIM + head * HD;
            op[lm]      = f2b(aA0[r] * inv);
            op[16 + lm] = f2b(aA1[r] * inv);
        }
    }
    if (dual) {
        #pragma unroll
        for (int r = 0; r < 4; ++r) {
            int qrowB = qtB * 16 + q4 * 4 + r;
            if (qrowB < NWT) {
                float inv = 1.0f / dnm[wid][1][q4 * 4 + r];
                unsigned short* op = o + (size_t)(bw * NWT + qrowB) * DIM + head * HD;
                op[lm]      = f2b(aB0[r] * inv);
                op[16 + lm] = f2b(aB1[r] * inv);
            }
        }
    }
}

// ---------------- K4: fused proj + reverse/roll + residual + LN2 + MLP ------
__global__ void __launch_bounds__(256) k_pm(
        const unsigned short* __restrict__ ao, const unsigned short* __restrict__ Wp,
        const float* __restrict__ pbias, const float* __restrict__ xin,
        float* __restrict__ xout,
        const float* __restrict__ g2, const float* __restrict__ b2,
        const unsigned short* __restrict__ w1, const float* __restrict__ bb1,
        const unsigned short* __restrict__ w2, const float* __restrict__ bb2,
        int shift) {
    __shared__ __align__(16) unsigned short lns[64][104];   // 13312 B
    __shared__ __align__(16) unsigned short big[18816];     // 37632 B
    int wid = threadIdx.x >> 6, lane = threadIdx.x & 63;
    int lm = lane & 15, q4 = lane >> 4;
    int m0 = blockIdx.x * 64 + wid * 16;
    for (int s = threadIdx.x; s < 1152; s += 256) {
        int row = s / 12, seg = s % 12;
        *((uint4*)&big[row * 104 + seg * 8]) = ((const uint4*)Wp)[s];
    }
    const unsigned short* arow = ao + (size_t)(m0 + lm) * 96;
    bf16x8 a1[3];
    #pragma unroll
    for (int ks = 0; ks < 3; ++ks)
        a1[ks] = *((const bf16x8*)(arow + ks * 32 + q4 * 8));
    __syncthreads();
    f32x4 acc[6];
    #pragma unroll
    for (int c = 0; c < 6; ++c) acc[c] = (f32x4){0.f, 0.f, 0.f, 0.f};
    #pragma unroll
    for (int ks = 0; ks < 3; ++ks) {
        #pragma unroll
        for (int c = 0; c < 6; ++c) {
            bf16x8 b = *((const bf16x8*)&big[(c * 16 + lm) * 104 + ks * 32 + q4 * 8]);
            acc[c] = __builtin_amdgcn_mfma_f32_16x16x32_bf16(a1[ks], b, acc[c], 0, 0, 0);
        }
    }
    size_t rowoff[4];
    #pragma unroll
    for (int r = 0; r < 4; ++r) {
        int wtok = m0 + q4 * 4 + r;
        int bw = wtok / NWT, n = wtok % NWT;
        int b = bw >> 6, win = bw & 63;
        int wdi = win >> 4, whi = (win >> 2) & 3, wwi = win & 3;
        int d = n / 49, h = (n / 7) % 7, w = n % 7;
        int sd = (wdi * 7 + d + shift) % 28;
        int sh = (whi * 7 + h + shift) % 28;
        int sw = (wwi * 7 + w + shift) % 28;
        rowoff[r] = (((size_t)(b * 28 + sd) * 28 + sh) * 28 + sw) * 96;
    }
    float val[6][4], g2v[6], b2v[6];
    #pragma unroll
    for (int c = 0; c < 6; ++c) {
        int n = c * 16 + lm;
        float bb = pbias[n];
        g2v[c] = g2[n]; b2v[c] = b2[n];
        #pragma unroll
        for (int r = 0; r < 4; ++r)
            val[c][r] = xin[rowoff[r] + n] + acc[c][r] + bb;
    }
    #pragma unroll
    for (int r = 0; r < 4; ++r) {
        float s = 0.f, s2 = 0.f;
        #pragma unroll
        for (int c = 0; c < 6; ++c) { s += val[c][r]; s2 += val[c][r] * val[c][r]; }
        #pragma unroll
        for (int off = 8; off > 0; off >>= 1) {
            s  += __shfl_xor(s,  off, 64);
            s2 += __shfl_xor(s2, off, 64);
        }
        float mu = s * (1.0f / 96.0f);
        float rstd = rsqrtf(s2 * (1.0f / 96.0f) - mu * mu + 1e-5f);
        int row = wid * 16 + q4 * 4 + r;
        #pragma unroll
        for (int c = 0; c < 6; ++c)
            lns[row][c * 16 + lm] = f2b((val[c][r] - mu) * rstd * g2v[c] + b2v[c]);
    }
    bf16x8 am[3];
    #pragma unroll
    for (int ks = 0; ks < 3; ++ks)
        am[ks] = *((const bf16x8*)&lns[wid * 16 + lm][ks * 32 + q4 * 8]);
    f32x4 acc2[6];
    #pragma unroll
    for (int c = 0; c < 6; ++c) acc2[c] = (f32x4){0.f, 0.f, 0.f, 0.f};
    unsigned short* hid_ = &big[13952 + wid * 1216];
    for (int ch = 0; ch < 6; ++ch) {
        __syncthreads();
        const uint4* src1 = (const uint4*)(w1 + ch * 64 * 96);
        #pragma unroll
        for (int t = 0; t < 3; ++t) {
            int s = threadIdx.x + t * 256;
            int row = s / 12, seg = s % 12;
            *((uint4*)&big[row * 104 + seg * 8]) = src1[s];
        }
        #pragma unroll
        for (int t = 0; t < 3; ++t) {
            int s = threadIdx.x + t * 256;
            int row = s >> 3, seg = s & 7;
            *((uint4*)&big[6656 + row * 76 + seg * 8]) =
                *((const uint4*)(w2 + row * 384 + ch * 64 + seg * 8));
        }
        __syncthreads();
        f32x4 acc1[4];
        #pragma unroll
        for (int t = 0; t < 4; ++t) acc1[t] = (f32x4){0.f, 0.f, 0.f, 0.f};
        #pragma unroll
        for (int ks = 0; ks < 3; ++ks) {
            #pragma unroll
            for (int t = 0; t < 4; ++t) {
                bf16x8 b = *((const bf16x8*)&big[(t * 16 + lm) * 104 + ks * 32 + q4 * 8]);
                acc1[t] = __builtin_amdgcn_mfma_f32_16x16x32_bf16(am[ks], b, acc1[t], 0, 0, 0);
            }
        }
        #pragma unroll
        for (int t = 0; t < 4; ++t) {
            float bb = bb1[ch * 64 + t * 16 + lm];
            #pragma unroll
            for (int r = 0; r < 4; ++r) {
                float v2 = acc1[t][r] + bb;
                float ge = 0.5f * v2 * (1.0f + erff(v2 * 0.70710678118654752f));
                hid_[(q4 * 4 + r) * 76 + t * 16 + lm] = f2b(ge);
            }
        }
        #pragma unroll
        for (int ks2 = 0; ks2 < 2; ++ks2) {
            bf16x8 a = *((const bf16x8*)(hid_ + lm * 76 + ks2 * 32 + q4 * 8));
            #pragma unroll
            for (int c = 0; c < 6; ++c) {
                bf16x8 b = *((const bf16x8*)&big[6656 + (c * 16 + lm) * 76 + ks2 * 32 + q4 * 8]);
                acc2[c] = __builtin_amdgcn_mfma_f32_16x16x32_bf16(a, b, acc2[c], 0, 0, 0);
            }
        }
    }
    #pragma unroll
    for (int c = 0; c < 6; ++c) {
        int n = c * 16 + lm;
        float bb = bb2[n];
        #pragma unroll
        for (int r = 0; r < 4; ++r)
            xout[rowoff[r] + n] = val[c][r] + acc2[c][r] + bb;
    }
}

extern "C" void kernel_launch(void* const* d_in, const int* in_sizes, int n_in,
                              void* d_out, int out_size, void* d_ws, size_t ws_size,
                              hipStream_t stream) {
    const float* x     = (const float*)d_in[0];
    const float* n1g   = (const float*)d_in[1];
    const float* n1b   = (const float*)d_in[2];
    const float* qkvw  = (const float*)d_in[3];
    const float* qkvb  = (const float*)d_in[4];
    const float* relb  = (const float*)d_in[5];
    const float* projw = (const float*)d_in[6];
    const float* projb = (const float*)d_in[7];
    const float* n2g   = (const float*)d_in[8];
    const float* n2b   = (const float*)d_in[9];
    const float* fc1w  = (const float*)d_in[10];
    const float* fc1b  = (const float*)d_in[11];
    const float* fc2w  = (const float*)d_in[12];
    const float* fc2b  = (const float*)d_in[13];
    float* out = (float*)d_out;

    const size_t NEL = (size_t)TOK * DIM;
    const size_t QKN = (size_t)NWIN * NHD * TPAD * 32;
    float* buf_x = (float*)d_ws;
    unsigned short* hbuf = (unsigned short*)(buf_x + NEL);  // attn out bf16 [tok][96]
    unsigned short* bq   = hbuf + NEL;       // [wh][352][32]
    unsigned short* bk   = bq + QKN;         // [wh][352][32]
    unsigned short* bv   = bk + QKN;         // [wh][32][352]  (V^T)
    unsigned short* wts  = bv + QKN;         // 221184 shorts
    unsigned short* wq  = wts;                 // 2 x 27648
    unsigned short* wp  = wq + 2 * 27648;      // 2 x 9216
    unsigned short* w1  = wp + 2 * 9216;       // 2 x 36864
    unsigned short* w2  = w1 + 2 * 36864;      // 2 x 36864
    float* btab = (float*)(wts + 221184);      // 9*3*343*352 floats = 13.0 MB

    k_cvt4<<<(221184 + 255) / 256, 256, 0, stream>>>(qkvw, projw, fc1w, fc2w, wts);
    k_bias<<<(9 * 3 * 343 * 352 + 255) / 256, 256, 0, stream>>>(
        relb, relb + NBIAS * NHD, btab);

    for (int L = 0; L < 2; ++L) {
        int shift = (L == 0) ? 0 : 3;
        const float* xin_l = (L == 0) ? x : buf_x;
        float* xfin = (L == 0) ? buf_x : out;
        const float* btL = (L == 0) ? btab : btab + 3 * TSZ;
        int tmul = (L == 0) ? 0 : 3 * TSZ;

        k_qkv<<<TOK / 64, 256, 0, stream>>>(xin_l, n1g + L * 96, n1b + L * 96,
                                            wq + L * 27648, qkvb + L * 288,
                                            bq, bk, bv, shift);
        k_attn<<<NWIN * NHD * 3, 256, 0, stream>>>(bq, bk, bv, btL, hbuf, tmul);
        k_pm<<<TOK / 64, 256, 0, stream>>>(hbuf, wp + L * 9216, projb + L * 96,
                                           xin_l, xfin,
                                           n2g + L * 96, n2b + L * 96,
                                           w1 + L * 36864, fc1b + L * 384,
                                           w2 + L * 36864, fc2b + L * 96, shift);
    }
}

// Round 10
// 261.351 us; speedup vs baseline: 1.1141x; 1.1141x over previous
//
#include <hip/hip_runtime.h>
#include <math.h>

#define DIM 96
#define NHD 3
#define HD 32
#define NWT 343          // tokens per window
#define NWIN 128         // b * windows
#define TOK 43904        // total tokens = 2*28^3
#define NBIAS 2197       // (2*7-1)^3
#define SCALE 0.17677669529663687f
#define TPAD 352         // padded token count per window (22 tiles of 16)
#define TSZ  (343 * 352) // one (combo,head) bias slice, elements

typedef __attribute__((ext_vector_type(8))) short bf16x8;
typedef __attribute__((ext_vector_type(4))) float f32x4;

__device__ __forceinline__ unsigned short f2b(float f) {
    union { float f; unsigned int u; } x; x.f = f;
    unsigned int r = (x.u + 0x7fffu + ((x.u >> 16) & 1u)) >> 16;
    return (unsigned short)r;
}
__device__ __forceinline__ unsigned int pk2bf(float a, float b) {
    union { float f; unsigned int u; } x, y; x.f = a; y.f = b;
    return ((x.u + 0x8000u) >> 16) | ((y.u + 0x8000u) & 0xffff0000u);
}
__device__ __forceinline__ float lo16(unsigned int u) {
    union { unsigned int u; float f; } x; x.u = u << 16; return x.f;
}
__device__ __forceinline__ float hi16(unsigned int u) {
    union { unsigned int u; float f; } x; x.u = u & 0xffff0000u; return x.f;
}

// ---------------- K0: all fp32 -> bf16 weight conversion, one launch --------
__global__ void __launch_bounds__(256) k_cvt4(
        const float* __restrict__ s0, const float* __restrict__ s1,
        const float* __restrict__ s2, const float* __restrict__ s3,
        unsigned short* __restrict__ dst) {
    int i = blockIdx.x * 256 + threadIdx.x;
    if (i >= 221184) return;
    const float* src; int off;
    if (i < 55296)       { src = s0; off = i; }
    else if (i < 73728)  { src = s1; off = i - 55296; }
    else if (i < 147456) { src = s2; off = i - 73728; }
    else                 { src = s3; off = i - 147456; }
    dst[i] = f2b(src[off]);
}

// ---------------- K1: bias+mask+pad table, bf16, fragment-permuted ----------
// combo 0: layer0 (no mask). combos 1..8: layer1, type = combo-1 (edge bits d,h,w)
// per q-row, permuted col c = pr*32 + q4*8 + j  -> orig k = pr*32 + (j>>2)*16 + q4*4 + (j&3)
__global__ void __launch_bounds__(256) k_bias(
        const float* __restrict__ rel0, const float* __restrict__ rel1,
        unsigned short* __restrict__ bt) {
    int i = blockIdx.x * 256 + threadIdx.x;
    if (i >= 9 * 3 * TSZ) return;
    int c = i % 352;
    int t = i / 352;
    int q = t % 343; t /= 343;
    int head = t % 3; int combo = t / 3;
    int j = c & 7, q4i = (c >> 3) & 3, pr = c >> 5;
    int kcol = pr * 32 + ((j >> 2) << 4) + q4i * 4 + (j & 3);
    float outv;
    if (kcol >= 343) {
        outv = -100000.0f;
    } else {
        int dq = q / 49, hq = (q / 7) % 7, wq = q % 7;
        int dk = kcol / 49, hk = (kcol / 7) % 7, wk = kcol % 7;
        int ridx = (dq - dk + 6) * 169 + (hq - hk + 6) * 13 + (wq - wk + 6);
        const float* rel = (combo == 0) ? rel0 : rel1;
        float b = rel[ridx * 3 + head];
        if (combo > 0) {
            int ty = combo - 1;
            int rqd = (ty & 4) ? 1 + (dq >= 4) : 0;
            int rqh = (ty & 2) ? 1 + (hq >= 4) : 0;
            int rqw = (ty & 1) ? 1 + (wq >= 4) : 0;
            int rkd = (ty & 4) ? 1 + (dk >= 4) : 0;
            int rkh = (ty & 2) ? 1 + (hk >= 4) : 0;
            int rkw = (ty & 1) ? 1 + (wk >= 4) : 0;
            if (rqd != rkd || rqh != rkh || rqw != rkw) b -= 100.0f;
        }
        outv = b;
    }
    bt[i] = f2b(outv);
}

// ---------------- K2: fused LN1 + roll + partition + QKV MFMA ---------------
__global__ void __launch_bounds__(256) k_qkv(
        const float* __restrict__ x, const float* __restrict__ g1,
        const float* __restrict__ b1, const unsigned short* __restrict__ W,
        const float* __restrict__ bias, unsigned short* __restrict__ q,
        unsigned short* __restrict__ k, unsigned short* __restrict__ v, int shift) {
    __shared__ __align__(16) unsigned short lns[64][104];   // 13312 B
    __shared__ __align__(16) unsigned short wbuf[96][104];  // 19968 B
    int wid = threadIdx.x >> 6, lane = threadIdx.x & 63;
    int lm = lane & 15, q4 = lane >> 4;
    int m0 = blockIdx.x * 64 + wid * 16;
    int bwr[4], nnr[4];
    size_t rowoff[4];
    #pragma unroll
    for (int r = 0; r < 4; ++r) {
        int wtok = m0 + q4 * 4 + r;
        int bw = wtok / NWT, n = wtok % NWT;
        bwr[r] = bw; nnr[r] = n;
        int b = bw >> 6, win = bw & 63;
        int wdi = win >> 4, whi = (win >> 2) & 3, wwi = win & 3;
        int d = n / 49, h = (n / 7) % 7, w = n % 7;
        int sd = (wdi * 7 + d + shift) % 28;
        int sh = (whi * 7 + h + shift) % 28;
        int sw = (wwi * 7 + w + shift) % 28;
        rowoff[r] = (((size_t)(b * 28 + sd) * 28 + sh) * 28 + sw) * 96;
    }
    float val[6][4], g1v[6], b1v[6];
    #pragma unroll
    for (int c = 0; c < 6; ++c) {
        int ncol = c * 16 + lm;
        g1v[c] = g1[ncol]; b1v[c] = b1[ncol];
        #pragma unroll
        for (int r = 0; r < 4; ++r) val[c][r] = x[rowoff[r] + ncol];
    }
    #pragma unroll
    for (int r = 0; r < 4; ++r) {
        float s = 0.f, s2 = 0.f;
        #pragma unroll
        for (int c = 0; c < 6; ++c) { s += val[c][r]; s2 += val[c][r] * val[c][r]; }
        #pragma unroll
        for (int off = 8; off > 0; off >>= 1) {
            s  += __shfl_xor(s,  off, 64);
            s2 += __shfl_xor(s2, off, 64);
        }
        float mu = s * (1.0f / 96.0f);
        float rstd = rsqrtf(s2 * (1.0f / 96.0f) - mu * mu + 1e-5f);
        int row = wid * 16 + q4 * 4 + r;
        #pragma unroll
        for (int c = 0; c < 6; ++c)
            lns[row][c * 16 + lm] = f2b((val[c][r] - mu) * rstd * g1v[c] + b1v[c]);
    }
    __syncthreads();
    bf16x8 a1[3];
    #pragma unroll
    for (int ks = 0; ks < 3; ++ks)
        a1[ks] = *((const bf16x8*)&lns[wid * 16 + lm][ks * 32 + q4 * 8]);
    for (int ch = 0; ch < 3; ++ch) {
        __syncthreads();
        const uint4* src = (const uint4*)(W + ch * 96 * 96);
        for (int s = threadIdx.x; s < 1152; s += 256) {
            int row = s / 12, seg = s % 12;
            *((uint4*)&wbuf[row][seg * 8]) = src[s];
        }
        __syncthreads();
        f32x4 acc[6];
        #pragma unroll
        for (int c = 0; c < 6; ++c) acc[c] = (f32x4){0.f, 0.f, 0.f, 0.f};
        #pragma unroll
        for (int ks = 0; ks < 3; ++ks) {
            #pragma unroll
            for (int c = 0; c < 6; ++c) {
                bf16x8 b = *((const bf16x8*)&wbuf[c * 16 + lm][ks * 32 + q4 * 8]);
                acc[c] = __builtin_amdgcn_mfma_f32_16x16x32_bf16(a1[ks], b, acc[c], 0, 0, 0);
            }
        }
        #pragma unroll
        for (int c = 0; c < 6; ++c) {
            int col = c * 16 + lm;
            int head = col >> 5, hd = col & 31;
            float bb = bias[ch * 96 + col];
            #pragma unroll
            for (int r = 0; r < 4; ++r) {
                int wh = bwr[r] * NHD + head;
                float vv = acc[c][r] + bb;
                if (ch == 0)
                    q[(size_t)wh * (TPAD * 32) + nnr[r] * 32 + hd] = f2b(vv * SCALE);
                else if (ch == 1)
                    k[(size_t)wh * (TPAD * 32) + nnr[r] * 32 + hd] = f2b(vv);
                else
                    v[(size_t)wh * (32 * TPAD) + hd * TPAD + nnr[r]] = f2b(vv);
            }
        }
    }
}

// ---------------- K3: MFMA flash attention, bf16 bias table + prefetch ------
__global__ void __launch_bounds__(256) k_attn(
        const unsigned short* __restrict__ q, const unsigned short* __restrict__ k,
        const unsigned short* __restrict__ vT, const unsigned short* __restrict__ bt,
        unsigned short* __restrict__ o, int tmul) {
    __shared__ __align__(16) unsigned short vts[32 * 360];
    __shared__ __align__(16) unsigned short pbuf[4][2][16 * 40];
    int wh = blockIdx.x / 3, third = blockIdx.x % 3;
    int bw = wh / NHD, head = wh % NHD;
    const unsigned int* vsrc = (const unsigned int*)(vT + (size_t)wh * 32 * TPAD);
    unsigned int* vdst = (unsigned int*)vts;
    for (int i = threadIdx.x; i < 32 * 176; i += 256) {
        int row = i / 176, cc = i - row * 176;
        vdst[row * 180 + cc] = vsrc[i];
    }
    __syncthreads();
    int win = bw & 63;
    int wdi = win >> 4, whi = (win >> 2) & 3, wwi = win & 3;
    int type = ((wdi == 3) ? 4 : 0) | ((whi == 3) ? 2 : 0) | ((wwi == 3) ? 1 : 0);
    const unsigned short* bbase = bt + (size_t)type * tmul + (size_t)head * TSZ;
    int wid = threadIdx.x >> 6, lane = threadIdx.x & 63;
    int lm = lane & 15, q4 = lane >> 4;
    int tb = third * 8 + wid * 2;
    if (tb > 21) return;               // no barriers below
    bool dual = (tb + 1 <= 21);
    int qtA = tb, qtB = dual ? tb + 1 : tb;
    const unsigned short* qbase = q + (size_t)wh * TPAD * 32;
    const unsigned short* kbase = k + (size_t)wh * TPAD * 32;
    int qtokA = qtA * 16 + lm, qtokB = qtB * 16 + lm;
    bf16x8 qfA = *((const bf16x8*)(qbase + qtokA * 32 + q4 * 8));
    bf16x8 qfB = *((const bf16x8*)(qbase + qtokB * 32 + q4 * 8));
    const unsigned short* bpA = bbase + (size_t)min(qtokA, NWT - 1) * 352;
    const unsigned short* bpB = bbase + (size_t)min(qtokB, NWT - 1) * 352;
    f32x4 aA0 = (f32x4){0.f,0.f,0.f,0.f}, aA1 = aA0, aB0 = aA0, aB1 = aA0;
    float dA = 0.f, dB = 0.f;
    unsigned short* pbA = pbuf[wid][0];
    unsigned short* pbB = pbuf[wid][1];
    // software prefetch of step-0 K frags and bias
    bf16x8 kf0n = *((const bf16x8*)(kbase + lm * 32 + q4 * 8));
    bf16x8 kf1n = *((const bf16x8*)(kbase + (16 + lm) * 32 + q4 * 8));
    uint4 bAn = *((const uint4*)(bpA + q4 * 8));
    uint4 bBn = *((const uint4*)(bpB + q4 * 8));
    for (int pr = 0; pr < 11; ++pr) {
        int kb0 = pr * 32;
        bf16x8 kf0 = kf0n, kf1 = kf1n;
        uint4 uA = bAn, uB = bBn;
        if (pr < 10) {
            int kb1 = kb0 + 32;
            kf0n = *((const bf16x8*)(kbase + (kb1 + lm) * 32 + q4 * 8));
            kf1n = *((const bf16x8*)(kbase + (kb1 + 16 + lm) * 32 + q4 * 8));
            bAn = *((const uint4*)(bpA + kb1 + q4 * 8));
            bBn = *((const uint4*)(bpB + kb1 + q4 * 8));
        }
        f32x4 z = (f32x4){0.f, 0.f, 0.f, 0.f};
        f32x4 sA0 = __builtin_amdgcn_mfma_f32_16x16x32_bf16(kf0, qfA, z, 0, 0, 0);
        f32x4 sA1 = __builtin_amdgcn_mfma_f32_16x16x32_bf16(kf1, qfA, z, 0, 0, 0);
        f32x4 sB0 = __builtin_amdgcn_mfma_f32_16x16x32_bf16(kf0, qfB, z, 0, 0, 0);
        f32x4 sB1 = __builtin_amdgcn_mfma_f32_16x16x32_bf16(kf1, qfB, z, 0, 0, 0);
        float pA[8], pB[8];
        pA[0] = __expf(sA0[0] + lo16(uA.x)); pA[1] = __expf(sA0[1] + hi16(uA.x));
        pA[2] = __expf(sA0[2] + lo16(uA.y)); pA[3] = __expf(sA0[3] + hi16(uA.y));
        pA[4] = __expf(sA1[0] + lo16(uA.z)); pA[5] = __expf(sA1[1] + hi16(uA.z));
        pA[6] = __expf(sA1[2] + lo16(uA.w)); pA[7] = __expf(sA1[3] + hi16(uA.w));
        pB[0] = __expf(sB0[0] + lo16(uB.x)); pB[1] = __expf(sB0[1] + hi16(uB.x));
        pB[2] = __expf(sB0[2] + lo16(uB.y)); pB[3] = __expf(sB0[3] + hi16(uB.y));
        pB[4] = __expf(sB1[0] + lo16(uB.z)); pB[5] = __expf(sB1[1] + hi16(uB.z));
        pB[6] = __expf(sB1[2] + lo16(uB.w)); pB[7] = __expf(sB1[3] + hi16(uB.w));
        #pragma unroll
        for (int j = 0; j < 8; ++j) { dA += pA[j]; dB += pB[j]; }
        #pragma unroll
        for (int t = 0; t < 2; ++t) {
            *((unsigned int*)(pbA + lm * 40 + t * 16 + q4 * 4)) =
                pk2bf(pA[t * 4 + 0], pA[t * 4 + 1]);
            *((unsigned int*)(pbA + lm * 40 + t * 16 + q4 * 4 + 2)) =
                pk2bf(pA[t * 4 + 2], pA[t * 4 + 3]);
            *((unsigned int*)(pbB + lm * 40 + t * 16 + q4 * 4)) =
                pk2bf(pB[t * 4 + 0], pB[t * 4 + 1]);
            *((unsigned int*)(pbB + lm * 40 + t * 16 + q4 * 4 + 2)) =
                pk2bf(pB[t * 4 + 2], pB[t * 4 + 3]);
        }
        bf16x8 pfA = *((const bf16x8*)(pbA + lm * 40 + q4 * 8));
        bf16x8 pfB = *((const bf16x8*)(pbB + lm * 40 + q4 * 8));
        bf16x8 v0 = *((const bf16x8*)(vts + lm * 360 + kb0 + q4 * 8));
        bf16x8 v1 = *((const bf16x8*)(vts + (16 + lm) * 360 + kb0 + q4 * 8));
        aA0 = __builtin_amdgcn_mfma_f32_16x16x32_bf16(pfA, v0, aA0, 0, 0, 0);
        aA1 = __builtin_amdgcn_mfma_f32_16x16x32_bf16(pfA, v1, aA1, 0, 0, 0);
        aB0 = __builtin_amdgcn_mfma_f32_16x16x32_bf16(pfB, v0, aB0, 0, 0, 0);
        aB1 = __builtin_amdgcn_mfma_f32_16x16x32_bf16(pfB, v1, aB1, 0, 0, 0);
    }
    dA += __shfl_xor(dA, 16, 64); dA += __shfl_xor(dA, 32, 64);
    dB += __shfl_xor(dB, 16, 64); dB += __shfl_xor(dB, 32, 64);
    #pragma unroll
    for (int r = 0; r < 4; ++r) {
        int qrowA = qtA * 16 + q4 * 4 + r;
        if (qrowA < NWT) {
            float inv = 1.0f / __shfl(dA, q4 * 4 + r, 64);
            unsigned short* op = o + (size_t)(bw * NWT + qrowA) * DIM + head * HD;
            op[lm]      = f2b(aA0[r] * inv);
            op[16 + lm] = f2b(aA1[r] * inv);
        }
    }
    if (dual) {
        #pragma unroll
        for (int r = 0; r < 4; ++r) {
            int qrowB = qtB * 16 + q4 * 4 + r;
            if (qrowB < NWT) {
                float inv = 1.0f / __shfl(dB, q4 * 4 + r, 64);
                unsigned short* op = o + (size_t)(bw * NWT + qrowB) * DIM + head * HD;
                op[lm]      = f2b(aB0[r] * inv);
                op[16 + lm] = f2b(aB1[r] * inv);
            }
        }
    }
}

// ---------------- K4: fused proj + reverse/roll + residual + LN2 + MLP ------
__global__ void __launch_bounds__(256) k_pm(
        const unsigned short* __restrict__ ao, const unsigned short* __restrict__ Wp,
        const float* __restrict__ pbias, const float* __restrict__ xin,
        float* __restrict__ xout,
        const float* __restrict__ g2, const float* __restrict__ b2,
        const unsigned short* __restrict__ w1, const float* __restrict__ bb1,
        const unsigned short* __restrict__ w2, const float* __restrict__ bb2,
        int shift) {
    __shared__ __align__(16) unsigned short lns[64][104];   // 13312 B
    __shared__ __align__(16) unsigned short big[18816];     // 37632 B
    int wid = threadIdx.x >> 6, lane = threadIdx.x & 63;
    int lm = lane & 15, q4 = lane >> 4;
    int m0 = blockIdx.x * 64 + wid * 16;
    for (int s = threadIdx.x; s < 1152; s += 256) {
        int row = s / 12, seg = s % 12;
        *((uint4*)&big[row * 104 + seg * 8]) = ((const uint4*)Wp)[s];
    }
    const unsigned short* arow = ao + (size_t)(m0 + lm) * 96;
    bf16x8 a1[3];
    #pragma unroll
    for (int ks = 0; ks < 3; ++ks)
        a1[ks] = *((const bf16x8*)(arow + ks * 32 + q4 * 8));
    __syncthreads();
    f32x4 acc[6];
    #pragma unroll
    for (int c = 0; c < 6; ++c) acc[c] = (f32x4){0.f, 0.f, 0.f, 0.f};
    #pragma unroll
    for (int ks = 0; ks < 3; ++ks) {
        #pragma unroll
        for (int c = 0; c < 6; ++c) {
            bf16x8 b = *((const bf16x8*)&big[(c * 16 + lm) * 104 + ks * 32 + q4 * 8]);
            acc[c] = __builtin_amdgcn_mfma_f32_16x16x32_bf16(a1[ks], b, acc[c], 0, 0, 0);
        }
    }
    size_t rowoff[4];
    #pragma unroll
    for (int r = 0; r < 4; ++r) {
        int wtok = m0 + q4 * 4 + r;
        int bw = wtok / NWT, n = wtok % NWT;
        int b = bw >> 6, win = bw & 63;
        int wdi = win >> 4, whi = (win >> 2) & 3, wwi = win & 3;
        int d = n / 49, h = (n / 7) % 7, w = n % 7;
        int sd = (wdi * 7 + d + shift) % 28;
        int sh = (whi * 7 + h + shift) % 28;
        int sw = (wwi * 7 + w + shift) % 28;
        rowoff[r] = (((size_t)(b * 28 + sd) * 28 + sh) * 28 + sw) * 96;
    }
    float val[6][4], g2v[6], b2v[6];
    #pragma unroll
    for (int c = 0; c < 6; ++c) {
        int n = c * 16 + lm;
        float bb = pbias[n];
        g2v[c] = g2[n]; b2v[c] = b2[n];
        #pragma unroll
        for (int r = 0; r < 4; ++r)
            val[c][r] = xin[rowoff[r] + n] + acc[c][r] + bb;
    }
    #pragma unroll
    for (int r = 0; r < 4; ++r) {
        float s = 0.f, s2 = 0.f;
        #pragma unroll
        for (int c = 0; c < 6; ++c) { s += val[c][r]; s2 += val[c][r] * val[c][r]; }
        #pragma unroll
        for (int off = 8; off > 0; off >>= 1) {
            s  += __shfl_xor(s,  off, 64);
            s2 += __shfl_xor(s2, off, 64);
        }
        float mu = s * (1.0f / 96.0f);
        float rstd = rsqrtf(s2 * (1.0f / 96.0f) - mu * mu + 1e-5f);
        int row = wid * 16 + q4 * 4 + r;
        #pragma unroll
        for (int c = 0; c < 6; ++c)
            lns[row][c * 16 + lm] = f2b((val[c][r] - mu) * rstd * g2v[c] + b2v[c]);
    }
    bf16x8 am[3];
    #pragma unroll
    for (int ks = 0; ks < 3; ++ks)
        am[ks] = *((const bf16x8*)&lns[wid * 16 + lm][ks * 32 + q4 * 8]);
    f32x4 acc2[6];
    #pragma unroll
    for (int c = 0; c < 6; ++c) acc2[c] = (f32x4){0.f, 0.f, 0.f, 0.f};
    unsigned short* hid_ = &big[13952 + wid * 1216];
    for (int ch = 0; ch < 6; ++ch) {
        __syncthreads();
        const uint4* src1 = (const uint4*)(w1 + ch * 64 * 96);
        #pragma unroll
        for (int t = 0; t < 3; ++t) {
            int s = threadIdx.x + t * 256;
            int row = s / 12, seg = s % 12;
            *((uint4*)&big[row * 104 + seg * 8]) = src1[s];
        }
        #pragma unroll
        for (int t = 0; t < 3; ++t) {
            int s = threadIdx.x + t * 256;
            int row = s >> 3, seg = s & 7;
            *((uint4*)&big[6656 + row * 76 + seg * 8]) =
                *((const uint4*)(w2 + row * 384 + ch * 64 + seg * 8));
        }
        __syncthreads();
        f32x4 acc1[4];
        #pragma unroll
        for (int t = 0; t < 4; ++t) acc1[t] = (f32x4){0.f, 0.f, 0.f, 0.f};
        #pragma unroll
        for (int ks = 0; ks < 3; ++ks) {
            #pragma unroll
            for (int t = 0; t < 4; ++t) {
                bf16x8 b = *((const bf16x8*)&big[(t * 16 + lm) * 104 + ks * 32 + q4 * 8]);
                acc1[t] = __builtin_amdgcn_mfma_f32_16x16x32_bf16(am[ks], b, acc1[t], 0, 0, 0);
            }
        }
        #pragma unroll
        for (int t = 0; t < 4; ++t) {
            float bb = bb1[ch * 64 + t * 16 + lm];
            #pragma unroll
            for (int r = 0; r < 4; ++r) {
                float v2 = acc1[t][r] + bb;
                float ge = 0.5f * v2 * (1.0f + erff(v2 * 0.70710678118654752f));
                hid_[(q4 * 4 + r) * 76 + t * 16 + lm] = f2b(ge);
            }
        }
        #pragma unroll
        for (int ks2 = 0; ks2 < 2; ++ks2) {
            bf16x8 a = *((const bf16x8*)(hid_ + lm * 76 + ks2 * 32 + q4 * 8));
            #pragma unroll
            for (int c = 0; c < 6; ++c) {
                bf16x8 b = *((const bf16x8*)&big[6656 + (c * 16 + lm) * 76 + ks2 * 32 + q4 * 8]);
                acc2[c] = __builtin_amdgcn_mfma_f32_16x16x32_bf16(a, b, acc2[c], 0, 0, 0);
            }
        }
    }
    #pragma unroll
    for (int c = 0; c < 6; ++c) {
        int n = c * 16 + lm;
        float bb = bb2[n];
        #pragma unroll
        for (int r = 0; r < 4; ++r)
            xout[rowoff[r] + n] = val[c][r] + acc2[c][r] + bb;
    }
}

extern "C" void kernel_launch(void* const* d_in, const int* in_sizes, int n_in,
                              void* d_out, int out_size, void* d_ws, size_t ws_size,
                              hipStream_t stream) {
    const float* x     = (const float*)d_in[0];
    const float* n1g   = (const float*)d_in[1];
    const float* n1b   = (const float*)d_in[2];
    const float* qkvw  = (const float*)d_in[3];
    const float* qkvb  = (const float*)d_in[4];
    const float* relb  = (const float*)d_in[5];
    const float* projw = (const float*)d_in[6];
    const float* projb = (const float*)d_in[7];
    const float* n2g   = (const float*)d_in[8];
    const float* n2b   = (const float*)d_in[9];
    const float* fc1w  = (const float*)d_in[10];
    const float* fc1b  = (const float*)d_in[11];
    const float* fc2w  = (const float*)d_in[12];
    const float* fc2b  = (const float*)d_in[13];
    float* out = (float*)d_out;

    const size_t NEL = (size_t)TOK * DIM;
    const size_t QKN = (size_t)NWIN * NHD * TPAD * 32;
    float* buf_x = (float*)d_ws;
    unsigned short* hbuf = (unsigned short*)(buf_x + NEL);  // attn out bf16 [tok][96]
    unsigned short* bq   = hbuf + NEL;       // [wh][352][32]
    unsigned short* bk   = bq + QKN;         // [wh][352][32]
    unsigned short* bv   = bk + QKN;         // [wh][32][352]  (V^T)
    unsigned short* wts  = bv + QKN;         // 221184 shorts
    unsigned short* wq  = wts;                 // 2 x 27648
    unsigned short* wp  = wq + 2 * 27648;      // 2 x 9216
    unsigned short* w1  = wp + 2 * 9216;       // 2 x 36864
    unsigned short* w2  = w1 + 2 * 36864;      // 2 x 36864
    unsigned short* btab = wts + 221184;       // 9*3*343*352 bf16 = 6.5 MB

    k_cvt4<<<(221184 + 255) / 256, 256, 0, stream>>>(qkvw, projw, fc1w, fc2w, wts);
    k_bias<<<(9 * 3 * TSZ + 255) / 256, 256, 0, stream>>>(
        relb, relb + NBIAS * NHD, btab);

    for (int L = 0; L < 2; ++L) {
        int shift = (L == 0) ? 0 : 3;
        const float* xin_l = (L == 0) ? x : buf_x;
        float* xfin = (L == 0) ? buf_x : out;
        const unsigned short* btL = (L == 0) ? btab : btab + 3 * TSZ;
        int tmul = (L == 0) ? 0 : 3 * TSZ;

        k_qkv<<<TOK / 64, 256, 0, stream>>>(xin_l, n1g + L * 96, n1b + L * 96,
                                            wq + L * 27648, qkvb + L * 288,
                                            bq, bk, bv, shift);
        k_attn<<<NWIN * NHD * 3, 256, 0, stream>>>(bq, bk, bv, btL, hbuf, tmul);
        k_pm<<<TOK / 64, 256, 0, stream>>>(hbuf, wp + L * 9216, projb + L * 96,
                                           xin_l, xfin,
                                           n2g + L * 96, n2b + L * 96,
                                           w1 + L * 36864, fc1b + L * 384,
                                           w2 + L * 36864, fc2b + L * 96, shift);
    }
}